// Round 7
// baseline (453.690 us; speedup 1.0000x reference)
//
#include <hip/hip_runtime.h>

// Problem constants
#define B_TOK 32768
#define D_IN  256
#define H1D   512
#define H2D   256
#define NE    16
#define NO    64

typedef _Float16 half8 __attribute__((ext_vector_type(8)));
typedef _Float16 half4 __attribute__((ext_vector_type(4)));
typedef float   float4_t __attribute__((ext_vector_type(4)));

// ---------------------------------------------------------------------------
// Fused prep kernel (grid 2066 x 256):
//  blocks 0..1023    : pack W1 [E][D][H1] fp32 -> fragment-linear fp16
//  blocks 1024..2047 : pack W2 [E][H1][H2] fp32 -> fragment-linear fp16
//  blocks 2048..2064 : w3h[e][h2] = W3[e][h2][:].head_w ; c3[e] = b3[e][:].head_w
//  block  2065       : pack gate_w [D][E] -> 8 B-fragments
// ---------------------------------------------------------------------------
__global__ void prep_kernel(const float* __restrict__ W1, const float* __restrict__ W2,
                            const float* __restrict__ W3, const float* __restrict__ b3,
                            const float* __restrict__ hw, const float* __restrict__ gw,
                            _Float16* __restrict__ w1p, _Float16* __restrict__ w2p,
                            float* __restrict__ w3h, float* __restrict__ c3,
                            _Float16* __restrict__ gwp) {
  int blk = blockIdx.x;
  int tid = threadIdx.x;
  if (blk < 1024) {
    int t = blk * 256 + tid;                     // 262144 threads
    int lane = t & 63;
    int kt   = (t >> 6) & 7;
    int ntg  = (t >> 9) & 31;
    int e    = t >> 14;
    int n  = ntg * 16 + (lane & 15);
    int kb = kt * 32 + (lane >> 4) * 8;
    half8 v;
    #pragma unroll
    for (int j = 0; j < 8; ++j)
      v[j] = (_Float16)W1[((size_t)(e * D_IN + kb + j)) * H1D + n];
    *(half8*)(w1p + (size_t)t * 8) = v;
  } else if (blk < 2048) {
    int t = (blk - 1024) * 256 + tid;            // 262144 threads
    int lane = t & 63;
    int ktg  = (t >> 6) & 15;
    int ntg  = (t >> 10) & 15;
    int e    = t >> 14;
    int n  = ntg * 16 + (lane & 15);
    int kb = ktg * 32 + (lane >> 4) * 8;
    half8 v;
    #pragma unroll
    for (int j = 0; j < 8; ++j)
      v[j] = (_Float16)W2[((size_t)(e * H1D + kb + j)) * H2D + n];
    *(half8*)(w2p + (size_t)t * 8) = v;
  } else if (blk < 2065) {
    int t = (blk - 2048) * 256 + tid;
    if (t < NE * H2D) {
      int e = t >> 8, h = t & 255;
      float s = 0.f;
      #pragma unroll
      for (int o = 0; o < NO; ++o) s = fmaf(W3[((size_t)(e * H2D + h)) * NO + o], hw[o], s);
      w3h[t] = s;
    } else if (t < NE * H2D + NE) {
      int e = t - NE * H2D;
      float s = 0.f;
      #pragma unroll
      for (int o = 0; o < NO; ++o) s = fmaf(b3[e * NO + o], hw[o], s);
      c3[e] = s;
    }
  } else {
    for (int t = tid; t < 512; t += 256) {
      int lane = t & 63;
      int kt   = t >> 6;
      int e  = lane & 15;
      int kb = kt * 32 + (lane >> 4) * 8;
      half8 v;
      #pragma unroll
      for (int j = 0; j < 8; ++j)
        v[j] = (_Float16)gw[(kb + j) * NE + e];
      *(half8*)(gwp + (size_t)t * 8) = v;
    }
  }
}

// ---------------------------------------------------------------------------
// Fused main kernel. 512 blocks x 256 threads (4 waves), 64 tokens/block,
// 2 blocks/CU. x staged once into LDS as fragment-linear fp16.
// h1: two 128-col chunk buffers (double-buffered). L1 runs as two 256-col
// register sweeps (x read once per sweep); each sweep's output is stored as
// two chunk-writes into alternating buffers. Every barrier interval mixes an
// L2 chunk with L1 sweep work -> MFMA/VMEM/LDS pipe overlap.
//   sweepA -> st(c0,buf0) B0 st(c1,buf1)+L2(0) B1 L2(1)+sweepB+st(c2,buf0)
//   B2 st(c3,buf1)+L2(2) B3 L2(3)+epilogue
// Deferred-gate epilogue; single shuffle-reduce at the end.
// ---------------------------------------------------------------------------
#define H1CSTR 136   // halves: 128 + 8 pad; 68 dw == 4 mod 32 -> free 2-way

__global__ __launch_bounds__(256, 2) void moe_main(
    const float* __restrict__ x,
    const float* __restrict__ b1,
    const float* __restrict__ b2,
    const _Float16* __restrict__ w1p,
    const _Float16* __restrict__ w2p,
    const _Float16* __restrict__ gwp,
    const float* __restrict__ gb,
    const float* __restrict__ w3h,
    const float* __restrict__ c3,
    const float* __restrict__ head_b,
    float* __restrict__ out) {
  __shared__ _Float16 x_lds[32 * 512];             // 32 KB fragment-linear
  __shared__ _Float16 h1c[2][64 * H1CSTR];         // 34,816 B (2 x 128-col)
  __shared__ float g_lds[64 * 17];                 // 4,352 B [token][e]
  __shared__ float fin[4 * 64];                    // 1,024 B

  const int tid  = threadIdx.x;
  const int w    = tid >> 6;
  const int lane = tid & 63;
  const int q    = lane >> 4;
  const int l16  = lane & 15;
  const int m0   = blockIdx.x * 64;

  // ---- stage x tile into LDS as MFMA fragments: frag (nt,kt) at
  //      x_lds[(nt*8+kt)*512 + lane*8]; wave w stages token tile w ----------
  #pragma unroll
  for (int f = 0; f < 8; ++f) {
    const float* xr = x + (size_t)(m0 + w * 16 + l16) * D_IN + f * 32 + q * 8;
    float4_t v0 = *(const float4_t*)(xr);
    float4_t v1 = *(const float4_t*)(xr + 4);
    half8 h;
    h[0] = (_Float16)v0[0]; h[1] = (_Float16)v0[1];
    h[2] = (_Float16)v0[2]; h[3] = (_Float16)v0[3];
    h[4] = (_Float16)v1[0]; h[5] = (_Float16)v1[1];
    h[6] = (_Float16)v1[2]; h[7] = (_Float16)v1[3];
    *(half8*)(x_lds + (size_t)(w * 8 + f) * 512 + lane * 8) = h;
  }
  __syncthreads();   // x_lds ready

  // ---- gates via MFMA + shuffle softmax; wave w handles token tile w ------
  {
    float gbv = gb[l16];
    float4_t lg = (float4_t){0.f, 0.f, 0.f, 0.f};
    #pragma unroll
    for (int kt = 0; kt < 8; ++kt) {
      half8 xa = *(const half8*)(x_lds + (size_t)(w * 8 + kt) * 512 + lane * 8);
      half8 bfr = *(const half8*)(gwp + (size_t)kt * 512 + lane * 8);
      lg = __builtin_amdgcn_mfma_f32_16x16x32_f16(xa, bfr, lg, 0, 0, 0);
    }
    #pragma unroll
    for (int r = 0; r < 4; ++r) {
      float v = lg[r] + gbv;                       // logit[token][e=l16]
      float m = v;
      m = fmaxf(m, __shfl_xor(m, 1));
      m = fmaxf(m, __shfl_xor(m, 2));
      m = fmaxf(m, __shfl_xor(m, 4));
      m = fmaxf(m, __shfl_xor(m, 8));
      float p = __expf(v - m);
      float s = p;
      s += __shfl_xor(s, 1);
      s += __shfl_xor(s, 2);
      s += __shfl_xor(s, 4);
      s += __shfl_xor(s, 8);
      g_lds[(w * 16 + q * 4 + r) * 17 + l16] = p / s;
    }
  }
  // g_lds becomes visible via in-loop barriers before first epilogue read.

  float yacc[4][4];    // gated accumulator: [mt][r] for token mt*16+q*4+r
  #pragma unroll
  for (int mt = 0; mt < 4; ++mt)
    #pragma unroll
    for (int r = 0; r < 4; ++r) yacc[mt][r] = 0.f;

  for (int e = 0; e < NE; ++e) {
    float4_t h2[4][4];
    #pragma unroll
    for (int mt = 0; mt < 4; ++mt)
      #pragma unroll
      for (int nt = 0; nt < 4; ++nt)
        h2[mt][nt] = (float4_t){0.f, 0.f, 0.f, 0.f};

    float4_t a1[4][4];   // [j][nt]; j -> col tiles of current sweep

    // L1 register sweep over 256 cols: j=0,1 -> chunk (2s) local tiles
    // w*2,w*2+1 ; j=2,3 -> chunk (2s+1) local tiles w*2,w*2+1.
    auto sweep = [&](int s) {
      #pragma unroll
      for (int j = 0; j < 4; ++j)
        #pragma unroll
        for (int nt = 0; nt < 4; ++nt)
          a1[j][nt] = (float4_t){0.f, 0.f, 0.f, 0.f};
      int tb = s * 16 + w * 2;   // global col-tile base for j=0
      const _Float16* w1e = w1p + (size_t)(e * 32 * 8) * 512 + lane * 8;
      #pragma unroll
      for (int kt = 0; kt < 8; ++kt) {
        half8 wv[4];
        wv[0] = *(const half8*)(w1e + (size_t)((tb + 0) * 8 + kt) * 512);
        wv[1] = *(const half8*)(w1e + (size_t)((tb + 1) * 8 + kt) * 512);
        wv[2] = *(const half8*)(w1e + (size_t)((tb + 8) * 8 + kt) * 512);
        wv[3] = *(const half8*)(w1e + (size_t)((tb + 9) * 8 + kt) * 512);
        half8 xv[4];
        #pragma unroll
        for (int nt = 0; nt < 4; ++nt)
          xv[nt] = *(const half8*)(x_lds + (size_t)(nt * 8 + kt) * 512 + lane * 8);
        #pragma unroll
        for (int j = 0; j < 4; ++j)
          #pragma unroll
          for (int nt = 0; nt < 4; ++nt)
            a1[j][nt] = __builtin_amdgcn_mfma_f32_16x16x32_f16(
                wv[j], xv[nt], a1[j][nt], 0, 0, 0);
      }
    };

    // store one 128-col chunk c from a1[j0..j0+1] (bias+relu, half4 stores)
    auto storechunk = [&](int c, int j0) {
      _Float16* buf = h1c[c & 1];
      #pragma unroll
      for (int i = 0; i < 2; ++i) {
        int lt = w * 2 + i;                        // local col tile in chunk
        int colbase = lt * 16 + q * 4;             // local col
        float4_t bb = *(const float4_t*)(b1 + e * H1D + c * 128 + colbase);
        #pragma unroll
        for (int nt = 0; nt < 4; ++nt) {
          half4 hv;
          #pragma unroll
          for (int r = 0; r < 4; ++r)
            hv[r] = (_Float16)fmaxf(a1[j0 + i][nt][r] + bb[r], 0.f);
          *(half4*)(buf + (nt * 16 + l16) * H1CSTR + colbase) = hv;
        }
      }
    };

    // L2 partial over one 128-col chunk c (4 k-tiles)
    auto l2chunk = [&](int c) {
      const _Float16* buf = h1c[c & 1];
      const _Float16* w2e =
          w2p + (size_t)((e * 16 + w * 4) * 16 + c * 4) * 512 + lane * 8;
      #pragma unroll
      for (int kt = 0; kt < 4; ++kt) {
        half8 w2c[4];
        #pragma unroll
        for (int nt = 0; nt < 4; ++nt)
          w2c[nt] = *(const half8*)(w2e + (size_t)(nt * 16 + kt) * 512);
        half8 hac[4];
        #pragma unroll
        for (int mt = 0; mt < 4; ++mt)
          hac[mt] = *(const half8*)(buf + (mt * 16 + l16) * H1CSTR + kt * 32 + q * 8);
        #pragma unroll
        for (int mt = 0; mt < 4; ++mt)
          #pragma unroll
          for (int nt = 0; nt < 4; ++nt)
            h2[mt][nt] = __builtin_amdgcn_mfma_f32_16x16x32_f16(
                hac[mt], w2c[nt], h2[mt][nt], 0, 0, 0);
      }
    };

    sweep(0);
    storechunk(0, 0);
    __syncthreads();                 // B0: chunk0 ready
    storechunk(1, 2);
    l2chunk(0);
    __syncthreads();                 // B1: chunk1 ready (chunk0 reads done)
    l2chunk(1);
    sweep(1);
    storechunk(2, 0);
    __syncthreads();                 // B2: chunk2 ready (chunk1 reads done)
    storechunk(3, 2);
    l2chunk(2);

    // hoist epilogue constants (global loads, independent of LDS)
    float b2v[4], w3v[4];
    #pragma unroll
    for (int nt = 0; nt < 4; ++nt) {
      int n = w * 64 + nt * 16 + l16;
      b2v[nt] = b2[e * H2D + n];
      w3v[nt] = w3h[e * H2D + n];
    }
    __syncthreads();                 // B3: chunk3 ready (chunk2 reads done)
    l2chunk(3);

    // ---- register epilogue: relu(h2+b2).w3h, gate folded, accumulate ------
    #pragma unroll
    for (int mt = 0; mt < 4; ++mt) {
      #pragma unroll
      for (int r = 0; r < 4; ++r) {
        float s = 0.f;
        #pragma unroll
        for (int nt = 0; nt < 4; ++nt)
          s += fmaxf(h2[mt][nt][r] + b2v[nt], 0.f) * w3v[nt];
        yacc[mt][r] += g_lds[(mt * 16 + q * 4 + r) * 17 + e] * s;
      }
    }
    // no extra barrier: next expert's first store (chunk0 -> buf0) is
    // separated from this expert's l2chunk(2) (buf0 reads) by B3 above;
    // l2chunk(3) reads buf1, next writer of buf1 is after next B0. safe.
  }

  // ---- single final reduction: sum yacc over the 16 l16-lanes (cols) ------
  #pragma unroll
  for (int mt = 0; mt < 4; ++mt) {
    #pragma unroll
    for (int r = 0; r < 4; ++r) {
      float v = yacc[mt][r];
      v += __shfl_xor(v, 1);
      v += __shfl_xor(v, 2);
      v += __shfl_xor(v, 4);
      v += __shfl_xor(v, 8);
      yacc[mt][r] = v;
    }
  }
  if (l16 == 0) {
    #pragma unroll
    for (int mt = 0; mt < 4; ++mt)
      #pragma unroll
      for (int r = 0; r < 4; ++r)
        fin[w * 64 + mt * 16 + q * 4 + r] = yacc[mt][r];
  }
  __syncthreads();
  if (tid < 64) {
    float sum = fin[tid] + fin[64 + tid] + fin[128 + tid] + fin[192 + tid];
    float gc = 0.f;
    #pragma unroll
    for (int e = 0; e < NE; ++e) gc += g_lds[tid * 17 + e] * c3[e];
    out[m0 + tid] = sum + gc + head_b[0];
  }
}

// ---------------------------------------------------------------------------
extern "C" void kernel_launch(void* const* d_in, const int* in_sizes, int n_in,
                              void* d_out, int out_size, void* d_ws, size_t ws_size,
                              hipStream_t stream) {
  const float* x      = (const float*)d_in[0];
  const float* gate_w = (const float*)d_in[1];
  const float* gate_b = (const float*)d_in[2];
  const float* W1     = (const float*)d_in[3];
  const float* b1     = (const float*)d_in[4];
  const float* W2     = (const float*)d_in[5];
  const float* b2     = (const float*)d_in[6];
  const float* W3     = (const float*)d_in[7];
  const float* b3     = (const float*)d_in[8];
  const float* head_w = (const float*)d_in[9];
  const float* head_b = (const float*)d_in[10];
  float* out = (float*)d_out;

  // workspace layout (16B-aligned)
  char* ws = (char*)d_ws;
  _Float16* w1p = (_Float16*)(ws);                 // 4,194,304 B
  _Float16* w2p = (_Float16*)(ws + 4194304);       // 4,194,304 B
  _Float16* gwp = (_Float16*)(ws + 8388608);       // 8,192 B
  float*    w3h = (float*)(ws + 8396800);          // 16,384 B
  float*    c3  = (float*)(ws + 8413184);          // 64 B

  hipLaunchKernelGGL(prep_kernel, dim3(2066), dim3(256), 0, stream,
                     W1, W2, W3, b3, head_w, gate_w, w1p, w2p, w3h, c3, gwp);
  hipLaunchKernelGGL(moe_main, dim3(B_TOK / 64), dim3(256), 0, stream,
                     x, b1, b2, w1p, w2p, gwp, gate_b, w3h, c3, head_b, out);
}

// Round 8
// 358.592 us; speedup vs baseline: 1.2652x; 1.2652x over previous
//
#include <hip/hip_runtime.h>

// Problem constants
#define B_TOK 32768
#define D_IN  256
#define H1D   512
#define H2D   256
#define NE    16
#define NO    64

typedef _Float16 half8 __attribute__((ext_vector_type(8)));
typedef _Float16 half4 __attribute__((ext_vector_type(4)));
typedef float   float4_t __attribute__((ext_vector_type(4)));

// ---------------------------------------------------------------------------
// Fused prep kernel (grid 2066 x 256):
//  blocks 0..1023    : pack W1 [E][D][H1] fp32 -> fragment-linear fp16
//  blocks 1024..2047 : pack W2 [E][H1][H2] fp32 -> fragment-linear fp16
//  blocks 2048..2064 : w3h[e][h2] = W3[e][h2][:].head_w ; c3[e] = b3[e][:].head_w
//  block  2065       : pack gate_w [D][E] -> 8 B-fragments
// ---------------------------------------------------------------------------
__global__ void prep_kernel(const float* __restrict__ W1, const float* __restrict__ W2,
                            const float* __restrict__ W3, const float* __restrict__ b3,
                            const float* __restrict__ hw, const float* __restrict__ gw,
                            _Float16* __restrict__ w1p, _Float16* __restrict__ w2p,
                            float* __restrict__ w3h, float* __restrict__ c3,
                            _Float16* __restrict__ gwp) {
  int blk = blockIdx.x;
  int tid = threadIdx.x;
  if (blk < 1024) {
    int t = blk * 256 + tid;                     // 262144 threads
    int lane = t & 63;
    int kt   = (t >> 6) & 7;
    int ntg  = (t >> 9) & 31;
    int e    = t >> 14;
    int n  = ntg * 16 + (lane & 15);
    int kb = kt * 32 + (lane >> 4) * 8;
    half8 v;
    #pragma unroll
    for (int j = 0; j < 8; ++j)
      v[j] = (_Float16)W1[((size_t)(e * D_IN + kb + j)) * H1D + n];
    *(half8*)(w1p + (size_t)t * 8) = v;
  } else if (blk < 2048) {
    int t = (blk - 1024) * 256 + tid;            // 262144 threads
    int lane = t & 63;
    int ktg  = (t >> 6) & 15;
    int ntg  = (t >> 10) & 15;
    int e    = t >> 14;
    int n  = ntg * 16 + (lane & 15);
    int kb = ktg * 32 + (lane >> 4) * 8;
    half8 v;
    #pragma unroll
    for (int j = 0; j < 8; ++j)
      v[j] = (_Float16)W2[((size_t)(e * H1D + kb + j)) * H2D + n];
    *(half8*)(w2p + (size_t)t * 8) = v;
  } else if (blk < 2065) {
    int t = (blk - 2048) * 256 + tid;
    if (t < NE * H2D) {
      int e = t >> 8, h = t & 255;
      float s = 0.f;
      #pragma unroll
      for (int o = 0; o < NO; ++o) s = fmaf(W3[((size_t)(e * H2D + h)) * NO + o], hw[o], s);
      w3h[t] = s;
    } else if (t < NE * H2D + NE) {
      int e = t - NE * H2D;
      float s = 0.f;
      #pragma unroll
      for (int o = 0; o < NO; ++o) s = fmaf(b3[e * NO + o], hw[o], s);
      c3[e] = s;
    }
  } else {
    for (int t = tid; t < 512; t += 256) {
      int lane = t & 63;
      int kt   = t >> 6;
      int e  = lane & 15;
      int kb = kt * 32 + (lane >> 4) * 8;
      half8 v;
      #pragma unroll
      for (int j = 0; j < 8; ++j)
        v[j] = (_Float16)gw[(kb + j) * NE + e];
      *(half8*)(gwp + (size_t)t * 8) = v;
    }
  }
}

// ---------------------------------------------------------------------------
// Fused main kernel. 512 blocks x 256 threads (4 waves), 64 tokens/block,
// 2 blocks/CU. x staged once into LDS as fragment-linear fp16.
// h1 chunk buffer is ALSO fragment-linear (A-operand layout): frag
// (token_tile mt, ktc) occupies 512 consecutive halves at (mt*8+ktc)*512,
// lane*8 within. -> L2's h1 reads are contiguous ds_read_b128 (same pattern
// as x_lds, minimal bank pressure); L1's stores are bank-uniform b64.
// Structure identical to R6: per expert, per 256-col chunk:
//   L1ch (w1 global + x LDS) -> h1ch(frag) -> barrier ->
//   L2ch-partial (h1ch LDS + w2 global) -> barrier (WAR)
// Deferred-gate epilogue in registers; single shuffle-reduce at the end.
// ---------------------------------------------------------------------------
__global__ __launch_bounds__(256, 2) void moe_main(
    const float* __restrict__ x,
    const float* __restrict__ b1,
    const float* __restrict__ b2,
    const _Float16* __restrict__ w1p,
    const _Float16* __restrict__ w2p,
    const _Float16* __restrict__ gwp,
    const float* __restrict__ gb,
    const float* __restrict__ w3h,
    const float* __restrict__ c3,
    const float* __restrict__ head_b,
    float* __restrict__ out) {
  __shared__ _Float16 x_lds[32 * 512];             // 32 KB fragment-linear
  __shared__ _Float16 h1c[32 * 512];               // 32 KB fragment-linear chunk
  __shared__ float g_lds[64 * 17];                 // 4,352 B [token][e]
  __shared__ float fin[4 * 64];                    // 1,024 B

  const int tid  = threadIdx.x;
  const int w    = tid >> 6;
  const int lane = tid & 63;
  const int q    = lane >> 4;
  const int l16  = lane & 15;
  const int m0   = blockIdx.x * 64;

  // ---- stage x tile into LDS as MFMA A-fragments: frag (nt,kt) at
  //      x_lds[(nt*8+kt)*512 + lane*8]; wave w stages token tile w ----------
  #pragma unroll
  for (int f = 0; f < 8; ++f) {
    const float* xr = x + (size_t)(m0 + w * 16 + l16) * D_IN + f * 32 + q * 8;
    float4_t v0 = *(const float4_t*)(xr);
    float4_t v1 = *(const float4_t*)(xr + 4);
    half8 h;
    h[0] = (_Float16)v0[0]; h[1] = (_Float16)v0[1];
    h[2] = (_Float16)v0[2]; h[3] = (_Float16)v0[3];
    h[4] = (_Float16)v1[0]; h[5] = (_Float16)v1[1];
    h[6] = (_Float16)v1[2]; h[7] = (_Float16)v1[3];
    *(half8*)(x_lds + (size_t)(w * 8 + f) * 512 + lane * 8) = h;
  }
  __syncthreads();   // x_lds ready

  // ---- gates via MFMA + shuffle softmax; wave w handles token tile w ------
  {
    float gbv = gb[l16];
    float4_t lg = (float4_t){0.f, 0.f, 0.f, 0.f};
    #pragma unroll
    for (int kt = 0; kt < 8; ++kt) {
      half8 xa = *(const half8*)(x_lds + (size_t)(w * 8 + kt) * 512 + lane * 8);
      half8 bfr = *(const half8*)(gwp + (size_t)kt * 512 + lane * 8);
      lg = __builtin_amdgcn_mfma_f32_16x16x32_f16(xa, bfr, lg, 0, 0, 0);
    }
    #pragma unroll
    for (int r = 0; r < 4; ++r) {
      float v = lg[r] + gbv;                       // logit[token][e=l16]
      float m = v;
      m = fmaxf(m, __shfl_xor(m, 1));
      m = fmaxf(m, __shfl_xor(m, 2));
      m = fmaxf(m, __shfl_xor(m, 4));
      m = fmaxf(m, __shfl_xor(m, 8));
      float p = __expf(v - m);
      float s = p;
      s += __shfl_xor(s, 1);
      s += __shfl_xor(s, 2);
      s += __shfl_xor(s, 4);
      s += __shfl_xor(s, 8);
      g_lds[(w * 16 + q * 4 + r) * 17 + l16] = p / s;
    }
  }
  // g_lds becomes visible via in-loop barriers before first epilogue read.

  float yacc[4][4];    // gated accumulator: [mt][r] for token mt*16+q*4+r
  #pragma unroll
  for (int mt = 0; mt < 4; ++mt)
    #pragma unroll
    for (int r = 0; r < 4; ++r) yacc[mt][r] = 0.f;

  for (int e = 0; e < NE; ++e) {
    float4_t h2[4][4];   // accumulates across both chunks
    #pragma unroll
    for (int mt = 0; mt < 4; ++mt)
      #pragma unroll
      for (int nt = 0; nt < 4; ++nt)
        h2[mt][nt] = (float4_t){0.f, 0.f, 0.f, 0.f};

    #pragma unroll
    for (int ch = 0; ch < 2; ++ch) {
      // ===== L1 chunk: h1[ch*256 .. +256) (transposed, A=W1^T, B=x) ========
      float4_t a1[4][4];   // [mt = wave's col tile][nt = token tile]
      #pragma unroll
      for (int mt = 0; mt < 4; ++mt)
        #pragma unroll
        for (int nt = 0; nt < 4; ++nt)
          a1[mt][nt] = (float4_t){0.f, 0.f, 0.f, 0.f};

      const _Float16* w1e =
          w1p + ((size_t)((e * 32 + ch * 16 + w * 4) * 8)) * 512 + lane * 8;
      #pragma unroll
      for (int kt = 0; kt < 8; ++kt) {
        half8 wc[4];
        #pragma unroll
        for (int mt = 0; mt < 4; ++mt)
          wc[mt] = *(const half8*)(w1e + (size_t)(mt * 8 + kt) * 512);
        half8 xb[4];
        #pragma unroll
        for (int nt = 0; nt < 4; ++nt)
          xb[nt] = *(const half8*)(x_lds + (size_t)(nt * 8 + kt) * 512 + lane * 8);
        #pragma unroll
        for (int mt = 0; mt < 4; ++mt)
          #pragma unroll
          for (int nt = 0; nt < 4; ++nt)
            a1[mt][nt] = __builtin_amdgcn_mfma_f32_16x16x32_f16(
                wc[mt], xb[nt], a1[mt][nt], 0, 0, 0);
      }

      // bias + relu + store into FRAGMENT-LINEAR chunk layout.
      // Value a1[mt][nt][r] = h1[tok = nt*16+l16][chunk col = lt*16+q*4+r],
      // lt = w*4+mt. Dest frag (nt, lt>>1), lane' = q'*16+l16 with
      // q' = (mt&1)*2 + (q>>1), half-offset (q&1)*4 + r  (r consecutive).
      // Verified: reader reconstructs col = lt*16 + q*4 + r exactly.
      #pragma unroll
      for (int mt = 0; mt < 4; ++mt) {
        int colbase = ch * 256 + (w * 4 + mt) * 16 + q * 4;  // global col
        float4_t bb = *(const float4_t*)(b1 + e * H1D + colbase);
        int qp = ((mt & 1) << 1) + (q >> 1);
        int fo = (qp * 16 + l16) * 8 + ((q & 1) << 2);
        #pragma unroll
        for (int nt = 0; nt < 4; ++nt) {
          half4 hv;
          #pragma unroll
          for (int r = 0; r < 4; ++r)
            hv[r] = (_Float16)fmaxf(a1[mt][nt][r] + bb[r], 0.f);
          *(half4*)(h1c + (size_t)(nt * 8 + w * 2 + (mt >> 1)) * 512 + fo) = hv;
        }
      }

      __syncthreads();   // h1 chunk ready

      // ===== L2 partial: h2 += h1c @ W2[ch*256.., wave's 64 cols] ==========
      const _Float16* w2e =
          w2p + ((size_t)((e * 16 + w * 4) * 16 + ch * 8)) * 512 + lane * 8;
      #pragma unroll
      for (int kt = 0; kt < 8; ++kt) {
        half8 w2c[4];
        #pragma unroll
        for (int nt = 0; nt < 4; ++nt)
          w2c[nt] = *(const half8*)(w2e + (size_t)(nt * 16 + kt) * 512);
        half8 hac[4];
        #pragma unroll
        for (int mt = 0; mt < 4; ++mt)
          hac[mt] = *(const half8*)(h1c + (size_t)(mt * 8 + kt) * 512 + lane * 8);
        #pragma unroll
        for (int mt = 0; mt < 4; ++mt)
          #pragma unroll
          for (int nt = 0; nt < 4; ++nt)
            h2[mt][nt] = __builtin_amdgcn_mfma_f32_16x16x32_f16(
                hac[mt], w2c[nt], h2[mt][nt], 0, 0, 0);
      }

      __syncthreads();   // WAR: h1c reads done before next chunk/expert L1
    }

    // ---- register epilogue: relu(h2+b2).w3h, gate folded, accumulate ------
    float b2v[4], w3v[4];
    #pragma unroll
    for (int nt = 0; nt < 4; ++nt) {
      int n = w * 64 + nt * 16 + l16;
      b2v[nt] = b2[e * H2D + n];
      w3v[nt] = w3h[e * H2D + n];
    }
    #pragma unroll
    for (int mt = 0; mt < 4; ++mt) {
      #pragma unroll
      for (int r = 0; r < 4; ++r) {
        float s = 0.f;
        #pragma unroll
        for (int nt = 0; nt < 4; ++nt)
          s += fmaxf(h2[mt][nt][r] + b2v[nt], 0.f) * w3v[nt];
        yacc[mt][r] += g_lds[(mt * 16 + q * 4 + r) * 17 + e] * s;
      }
    }
  }

  // ---- single final reduction: sum yacc over the 16 l16-lanes (cols) ------
  #pragma unroll
  for (int mt = 0; mt < 4; ++mt) {
    #pragma unroll
    for (int r = 0; r < 4; ++r) {
      float v = yacc[mt][r];
      v += __shfl_xor(v, 1);
      v += __shfl_xor(v, 2);
      v += __shfl_xor(v, 4);
      v += __shfl_xor(v, 8);
      yacc[mt][r] = v;
    }
  }
  if (l16 == 0) {
    #pragma unroll
    for (int mt = 0; mt < 4; ++mt)
      #pragma unroll
      for (int r = 0; r < 4; ++r)
        fin[w * 64 + mt * 16 + q * 4 + r] = yacc[mt][r];
  }
  __syncthreads();
  if (tid < 64) {
    float sum = fin[tid] + fin[64 + tid] + fin[128 + tid] + fin[192 + tid];
    float gc = 0.f;
    #pragma unroll
    for (int e = 0; e < NE; ++e) gc += g_lds[tid * 17 + e] * c3[e];
    out[m0 + tid] = sum + gc + head_b[0];
  }
}

// ---------------------------------------------------------------------------
extern "C" void kernel_launch(void* const* d_in, const int* in_sizes, int n_in,
                              void* d_out, int out_size, void* d_ws, size_t ws_size,
                              hipStream_t stream) {
  const float* x      = (const float*)d_in[0];
  const float* gate_w = (const float*)d_in[1];
  const float* gate_b = (const float*)d_in[2];
  const float* W1     = (const float*)d_in[3];
  const float* b1     = (const float*)d_in[4];
  const float* W2     = (const float*)d_in[5];
  const float* b2     = (const float*)d_in[6];
  const float* W3     = (const float*)d_in[7];
  const float* b3     = (const float*)d_in[8];
  const float* head_w = (const float*)d_in[9];
  const float* head_b = (const float*)d_in[10];
  float* out = (float*)d_out;

  // workspace layout (16B-aligned)
  char* ws = (char*)d_ws;
  _Float16* w1p = (_Float16*)(ws);                 // 4,194,304 B
  _Float16* w2p = (_Float16*)(ws + 4194304);       // 4,194,304 B
  _Float16* gwp = (_Float16*)(ws + 8388608);       // 8,192 B
  float*    w3h = (float*)(ws + 8396800);          // 16,384 B
  float*    c3  = (float*)(ws + 8413184);          // 64 B

  hipLaunchKernelGGL(prep_kernel, dim3(2066), dim3(256), 0, stream,
                     W1, W2, W3, b3, head_w, gate_w, w1p, w2p, w3h, c3, gwp);
  hipLaunchKernelGGL(moe_main, dim3(B_TOK / 64), dim3(256), 0, stream,
                     x, b1, b2, w1p, w2p, gwp, gate_b, w3h, c3, head_b, out);
}

// Round 9
// 344.001 us; speedup vs baseline: 1.3189x; 1.0424x over previous
//
#include <hip/hip_runtime.h>

// Problem constants
#define B_TOK 32768
#define D_IN  256
#define H1D   512
#define H2D   256
#define NE    16
#define NO    64
#define TK    128            // tokens per block

typedef _Float16 half8 __attribute__((ext_vector_type(8)));
typedef _Float16 half4 __attribute__((ext_vector_type(4)));
typedef float   float4_t __attribute__((ext_vector_type(4)));

// ---------------------------------------------------------------------------
// Fused prep kernel (grid 2066 x 256):
//  blocks 0..1023    : pack W1 [E][D][H1] fp32 -> fragment-linear fp16
//  blocks 1024..2047 : pack W2 [E][H1][H2] fp32 -> fragment-linear fp16
//  blocks 2048..2064 : w3h[e][h2] = W3[e][h2][:].head_w ; c3[e] = b3[e][:].head_w
//  block  2065       : pack gate_w [D][E] -> 8 B-fragments
// ---------------------------------------------------------------------------
__global__ void prep_kernel(const float* __restrict__ W1, const float* __restrict__ W2,
                            const float* __restrict__ W3, const float* __restrict__ b3,
                            const float* __restrict__ hw, const float* __restrict__ gw,
                            _Float16* __restrict__ w1p, _Float16* __restrict__ w2p,
                            float* __restrict__ w3h, float* __restrict__ c3,
                            _Float16* __restrict__ gwp) {
  int blk = blockIdx.x;
  int tid = threadIdx.x;
  if (blk < 1024) {
    int t = blk * 256 + tid;                     // 262144 threads
    int lane = t & 63;
    int kt   = (t >> 6) & 7;
    int ntg  = (t >> 9) & 31;
    int e    = t >> 14;
    int n  = ntg * 16 + (lane & 15);
    int kb = kt * 32 + (lane >> 4) * 8;
    half8 v;
    #pragma unroll
    for (int j = 0; j < 8; ++j)
      v[j] = (_Float16)W1[((size_t)(e * D_IN + kb + j)) * H1D + n];
    *(half8*)(w1p + (size_t)t * 8) = v;
  } else if (blk < 2048) {
    int t = (blk - 1024) * 256 + tid;            // 262144 threads
    int lane = t & 63;
    int ktg  = (t >> 6) & 15;
    int ntg  = (t >> 10) & 15;
    int e    = t >> 14;
    int n  = ntg * 16 + (lane & 15);
    int kb = ktg * 32 + (lane >> 4) * 8;
    half8 v;
    #pragma unroll
    for (int j = 0; j < 8; ++j)
      v[j] = (_Float16)W2[((size_t)(e * H1D + kb + j)) * H2D + n];
    *(half8*)(w2p + (size_t)t * 8) = v;
  } else if (blk < 2065) {
    int t = (blk - 2048) * 256 + tid;
    if (t < NE * H2D) {
      int e = t >> 8, h = t & 255;
      float s = 0.f;
      #pragma unroll
      for (int o = 0; o < NO; ++o) s = fmaf(W3[((size_t)(e * H2D + h)) * NO + o], hw[o], s);
      w3h[t] = s;
    } else if (t < NE * H2D + NE) {
      int e = t - NE * H2D;
      float s = 0.f;
      #pragma unroll
      for (int o = 0; o < NO; ++o) s = fmaf(b3[e * NO + o], hw[o], s);
      c3[e] = s;
    }
  } else {
    for (int t = tid; t < 512; t += 256) {
      int lane = t & 63;
      int kt   = t >> 6;
      int e  = lane & 15;
      int kb = kt * 32 + (lane >> 4) * 8;
      half8 v;
      #pragma unroll
      for (int j = 0; j < 8; ++j)
        v[j] = (_Float16)gw[(kb + j) * NE + e];
      *(half8*)(gwp + (size_t)t * 8) = v;
    }
  }
}

// ---------------------------------------------------------------------------
// Fused main kernel. 256 blocks x 512 threads (8 waves, 2/SIMD), 128 tok/blk,
// 1 block/CU -> per-CU weight L2 traffic HALVES vs 64-tok blocks (8 MB/CU).
// x and h1 both fragment-linear in LDS (R8-proven layout, conflict-free).
// Per expert, per 256-col chunk:
//   L1ch: wave w computes col-tiles {2w, 2w+1} x 8 token-tiles
//         (A=W1^T frags global, B=x frags LDS) -> frag-linear h1c -> barrier
//   L2ch: wave w computes h2col-tiles {2w, 2w+1} x 8 token-tiles
//         (A=h1c frags LDS, B=W2 frags global), accumulate -> barrier (WAR)
// Deferred-gate register epilogue; single shuffle-reduce at the end.
// ---------------------------------------------------------------------------
__global__ __launch_bounds__(512, 2) void moe_main(
    const float* __restrict__ x,
    const float* __restrict__ b1,
    const float* __restrict__ b2,
    const _Float16* __restrict__ w1p,
    const _Float16* __restrict__ w2p,
    const _Float16* __restrict__ gwp,
    const float* __restrict__ gb,
    const float* __restrict__ w3h,
    const float* __restrict__ c3,
    const float* __restrict__ head_b,
    float* __restrict__ out) {
  __shared__ _Float16 x_lds[64 * 512];             // 64 KB fragment-linear
  __shared__ _Float16 h1c[64 * 512];               // 64 KB fragment-linear chunk
  __shared__ float g_lds[TK * 17];                 // 8,704 B [token][e]
  __shared__ float fin[8 * TK];                    // 4 KB

  const int tid  = threadIdx.x;
  const int w    = tid >> 6;                       // 0..7
  const int lane = tid & 63;
  const int q    = lane >> 4;
  const int l16  = lane & 15;
  const int m0   = blockIdx.x * TK;

  // ---- stage x tile into LDS as MFMA A-fragments: frag (nt,kt) at
  //      x_lds[(nt*8+kt)*512 + lane*8]; wave w stages token tile w ----------
  #pragma unroll
  for (int f = 0; f < 8; ++f) {
    const float* xr = x + (size_t)(m0 + w * 16 + l16) * D_IN + f * 32 + q * 8;
    float4_t v0 = *(const float4_t*)(xr);
    float4_t v1 = *(const float4_t*)(xr + 4);
    half8 h;
    h[0] = (_Float16)v0[0]; h[1] = (_Float16)v0[1];
    h[2] = (_Float16)v0[2]; h[3] = (_Float16)v0[3];
    h[4] = (_Float16)v1[0]; h[5] = (_Float16)v1[1];
    h[6] = (_Float16)v1[2]; h[7] = (_Float16)v1[3];
    *(half8*)(x_lds + (size_t)(w * 8 + f) * 512 + lane * 8) = h;
  }
  __syncthreads();   // x_lds ready

  // ---- gates via MFMA + shuffle softmax; wave w handles token tile w ------
  {
    float gbv = gb[l16];
    float4_t lg = (float4_t){0.f, 0.f, 0.f, 0.f};
    #pragma unroll
    for (int kt = 0; kt < 8; ++kt) {
      half8 xa = *(const half8*)(x_lds + (size_t)(w * 8 + kt) * 512 + lane * 8);
      half8 bfr = *(const half8*)(gwp + (size_t)kt * 512 + lane * 8);
      lg = __builtin_amdgcn_mfma_f32_16x16x32_f16(xa, bfr, lg, 0, 0, 0);
    }
    #pragma unroll
    for (int r = 0; r < 4; ++r) {
      float v = lg[r] + gbv;                       // logit[token][e=l16]
      float m = v;
      m = fmaxf(m, __shfl_xor(m, 1));
      m = fmaxf(m, __shfl_xor(m, 2));
      m = fmaxf(m, __shfl_xor(m, 4));
      m = fmaxf(m, __shfl_xor(m, 8));
      float p = __expf(v - m);
      float s = p;
      s += __shfl_xor(s, 1);
      s += __shfl_xor(s, 2);
      s += __shfl_xor(s, 4);
      s += __shfl_xor(s, 8);
      g_lds[(w * 16 + q * 4 + r) * 17 + l16] = p / s;
    }
  }
  // g_lds becomes visible via in-loop barriers before first epilogue read.

  float yacc[8][4];    // gated accumulator: [mt][r] for token mt*16+q*4+r
  #pragma unroll
  for (int mt = 0; mt < 8; ++mt)
    #pragma unroll
    for (int r = 0; r < 4; ++r) yacc[mt][r] = 0.f;

  for (int e = 0; e < NE; ++e) {
    float4_t h2[8][2];   // [token tile][h2col tile j], accumulates over chunks
    #pragma unroll
    for (int mt = 0; mt < 8; ++mt)
      #pragma unroll
      for (int j = 0; j < 2; ++j)
        h2[mt][j] = (float4_t){0.f, 0.f, 0.f, 0.f};

    #pragma unroll
    for (int ch = 0; ch < 2; ++ch) {
      // ===== L1 chunk: wave w -> chunk col-tiles {2w, 2w+1} ================
      float4_t a1[2][8];   // [i = col tile][nt = token tile]
      #pragma unroll
      for (int i = 0; i < 2; ++i)
        #pragma unroll
        for (int nt = 0; nt < 8; ++nt)
          a1[i][nt] = (float4_t){0.f, 0.f, 0.f, 0.f};

      const _Float16* w1e =
          w1p + ((size_t)((e * 32 + ch * 16 + w * 2) * 8)) * 512 + lane * 8;
      #pragma unroll
      for (int kt = 0; kt < 8; ++kt) {
        half8 wc[2];
        #pragma unroll
        for (int i = 0; i < 2; ++i)
          wc[i] = *(const half8*)(w1e + (size_t)(i * 8 + kt) * 512);
        half8 xb[8];
        #pragma unroll
        for (int nt = 0; nt < 8; ++nt)
          xb[nt] = *(const half8*)(x_lds + (size_t)(nt * 8 + kt) * 512 + lane * 8);
        #pragma unroll
        for (int i = 0; i < 2; ++i)
          #pragma unroll
          for (int nt = 0; nt < 8; ++nt)
            a1[i][nt] = __builtin_amdgcn_mfma_f32_16x16x32_f16(
                wc[i], xb[nt], a1[i][nt], 0, 0, 0);
      }

      // bias + relu + store into FRAGMENT-LINEAR chunk layout.
      // a1[i][nt][r] = h1[tok = nt*16+l16][chunk col = (2w+i)*16 + q*4 + r].
      // chunk k-tile ktc = (2w+i)>>1 = w; lane' q' = 2i + (q>>1);
      // half-offset (q&1)*4 + r (consecutive). Verified vs A-operand reader.
      #pragma unroll
      for (int i = 0; i < 2; ++i) {
        int colbase = ch * 256 + (w * 2 + i) * 16 + q * 4;   // global h1 col
        float4_t bb = *(const float4_t*)(b1 + e * H1D + colbase);
        int qp = (i << 1) + (q >> 1);
        int fo = (qp * 16 + l16) * 8 + ((q & 1) << 2);
        #pragma unroll
        for (int nt = 0; nt < 8; ++nt) {
          half4 hv;
          #pragma unroll
          for (int r = 0; r < 4; ++r)
            hv[r] = (_Float16)fmaxf(a1[i][nt][r] + bb[r], 0.f);
          *(half4*)(h1c + (size_t)(nt * 8 + w) * 512 + fo) = hv;
        }
      }

      __syncthreads();   // h1 chunk ready

      // ===== L2 partial: wave w -> h2col-tiles {2w, 2w+1} ==================
      const _Float16* w2e =
          w2p + ((size_t)((e * 16 + w * 2) * 16 + ch * 8)) * 512 + lane * 8;
      #pragma unroll
      for (int kt = 0; kt < 8; ++kt) {
        half8 w2c[2];
        #pragma unroll
        for (int j = 0; j < 2; ++j)
          w2c[j] = *(const half8*)(w2e + (size_t)(j * 16 + kt) * 512);
        half8 hac[8];
        #pragma unroll
        for (int mt = 0; mt < 8; ++mt)
          hac[mt] = *(const half8*)(h1c + (size_t)(mt * 8 + kt) * 512 + lane * 8);
        #pragma unroll
        for (int mt = 0; mt < 8; ++mt)
          #pragma unroll
          for (int j = 0; j < 2; ++j)
            h2[mt][j] = __builtin_amdgcn_mfma_f32_16x16x32_f16(
                hac[mt], w2c[j], h2[mt][j], 0, 0, 0);
      }

      __syncthreads();   // WAR: h1c reads done before next chunk/expert L1
    }

    // ---- register epilogue: relu(h2+b2).w3h, gate folded, accumulate ------
    float b2v[2], w3v[2];
    #pragma unroll
    for (int j = 0; j < 2; ++j) {
      int n = (w * 2 + j) * 16 + l16;
      b2v[j] = b2[e * H2D + n];
      w3v[j] = w3h[e * H2D + n];
    }
    #pragma unroll
    for (int mt = 0; mt < 8; ++mt) {
      #pragma unroll
      for (int r = 0; r < 4; ++r) {
        float s = 0.f;
        #pragma unroll
        for (int j = 0; j < 2; ++j)
          s += fmaxf(h2[mt][j][r] + b2v[j], 0.f) * w3v[j];
        yacc[mt][r] += g_lds[(mt * 16 + q * 4 + r) * 17 + e] * s;
      }
    }
  }

  // ---- single final reduction: sum yacc over the 16 l16-lanes (cols) ------
  #pragma unroll
  for (int mt = 0; mt < 8; ++mt) {
    #pragma unroll
    for (int r = 0; r < 4; ++r) {
      float v = yacc[mt][r];
      v += __shfl_xor(v, 1);
      v += __shfl_xor(v, 2);
      v += __shfl_xor(v, 4);
      v += __shfl_xor(v, 8);
      yacc[mt][r] = v;
    }
  }
  if (l16 == 0) {
    #pragma unroll
    for (int mt = 0; mt < 8; ++mt)
      #pragma unroll
      for (int r = 0; r < 4; ++r)
        fin[w * TK + mt * 16 + q * 4 + r] = yacc[mt][r];
  }
  __syncthreads();
  if (tid < TK) {
    float sum = 0.f;
    #pragma unroll
    for (int k = 0; k < 8; ++k) sum += fin[k * TK + tid];
    float gc = 0.f;
    #pragma unroll
    for (int e = 0; e < NE; ++e) gc += g_lds[tid * 17 + e] * c3[e];
    out[m0 + tid] = sum + gc + head_b[0];
  }
}

// ---------------------------------------------------------------------------
extern "C" void kernel_launch(void* const* d_in, const int* in_sizes, int n_in,
                              void* d_out, int out_size, void* d_ws, size_t ws_size,
                              hipStream_t stream) {
  const float* x      = (const float*)d_in[0];
  const float* gate_w = (const float*)d_in[1];
  const float* gate_b = (const float*)d_in[2];
  const float* W1     = (const float*)d_in[3];
  const float* b1     = (const float*)d_in[4];
  const float* W2     = (const float*)d_in[5];
  const float* b2     = (const float*)d_in[6];
  const float* W3     = (const float*)d_in[7];
  const float* b3     = (const float*)d_in[8];
  const float* head_w = (const float*)d_in[9];
  const float* head_b = (const float*)d_in[10];
  float* out = (float*)d_out;

  // workspace layout (16B-aligned)
  char* ws = (char*)d_ws;
  _Float16* w1p = (_Float16*)(ws);                 // 4,194,304 B
  _Float16* w2p = (_Float16*)(ws + 4194304);       // 4,194,304 B
  _Float16* gwp = (_Float16*)(ws + 8388608);       // 8,192 B
  float*    w3h = (float*)(ws + 8396800);          // 16,384 B
  float*    c3  = (float*)(ws + 8413184);          // 64 B

  hipLaunchKernelGGL(prep_kernel, dim3(2066), dim3(256), 0, stream,
                     W1, W2, W3, b3, head_w, gate_w, w1p, w2p, w3h, c3, gwp);
  hipLaunchKernelGGL(moe_main, dim3(B_TOK / TK), dim3(512), 0, stream,
                     x, b1, b2, w1p, w2p, gwp, gate_b, w3h, c3, head_b, out);
}